// Round 5
// baseline (60.643 us; speedup 1.0000x reference)
//
#include <hip/hip_runtime.h>
#include <hip/hip_bf16.h>
#include <math.h>

#define B_ 16
#define T_ 128
#define H_ 8
#define N_ 64
#define NCHUNK 8
#define CHUNK (T_ / NCHUNK)   // 16
#define NUNITS (B_ * N_ * NCHUNK)  // 8192

#define K_ENT 4.0f   // variance shift for entropy (ent ~ 3.9); exact math for any K
#define K_DIF 0.75f  // variance shift for diff

// ---- cross-lane add helpers -------------------------------------------------
// DPP (VALU pipe, ~2cy): xor1 = quad_perm[1,0,3,2] (0xB1), xor2 = quad_perm
// [2,3,0,1] (0x4E), xor8 = row_ror:8 (0x128; rotation by 8 in a 16-lane row
// == lane^8). ds_swizzle (DS pipe) only for xor4 (0x101F) / xor16 (0x401F);
// __shfl_xor for 32 (ds_permute).
template <int CTRL>
__device__ __forceinline__ float dpp_xadd(float x) {
  const int yi = __builtin_amdgcn_update_dpp(
      __float_as_int(x), __float_as_int(x), CTRL, 0xf, 0xf, false);
  return x + __int_as_float(yi);
}
template <int IMM>
__device__ __forceinline__ float swz_xadd(float x) {
  return x + __int_as_float(
                 __builtin_amdgcn_ds_swizzle(__float_as_int(x), IMM));
}
// sum over q (lane&7): masks {1,2,4}
__device__ __forceinline__ float qsum(float x) {
  x = dpp_xadd<0xB1>(x);
  x = dpp_xadd<0x4E>(x);
  x = swz_xadd<0x101F>(x);
  return x;
}
// sum over h (lane>>3): masks {8,16,32}
__device__ __forceinline__ float hsum(float x) {
  x = dpp_xadd<0x128>(x);
  x = swz_xadd<0x401F>(x);
  x += __shfl_xor(x, 32, 64);
  return x;
}
// full 64-lane sum
__device__ __forceinline__ float fsum(float x) {
  x = dpp_xadd<0xB1>(x);
  x = dpp_xadd<0x4E>(x);
  x = swz_xadd<0x101F>(x);
  x = dpp_xadd<0x128>(x);
  x = swz_xadd<0x401F>(x);
  x += __shfl_xor(x, 32, 64);
  return x;
}

// ---------------------------------------------------------------------------
// Kernel 1: one WAVE per (b, n, chunk). Lane l = h*8 + q: head h owns cols
// [4q,4q+4) and [32+4q,32+4q+4). Two timesteps per iteration. No max-shift
// (|logits| < ~7 -> exp safe in fp32). Reduces mostly on DPP (VALU pipe).
// ---------------------------------------------------------------------------
__global__ __launch_bounds__(256) void feat_partial_kernel(
    const float* __restrict__ sat, float* __restrict__ part) {
  const int wave = threadIdx.x >> 6;
  const int lane = threadIdx.x & 63;
  const int unit = blockIdx.x * 4 + wave;   // c*1024 + b*64 + n
  const int c = unit >> 10;
  const int bn = unit & 1023;
  const int b = bn >> 6;
  const int n = bn & 63;

  const int q = lane & 7;
  const int h = lane >> 3;

  const int t0 = c * CHUNK;

  const long long tstride = (long long)H_ * N_ * N_;  // 32768 elems
  const float* rowp = sat +
      ((((long long)(b * T_ + t0) * H_ + h) * N_ + n) * N_) + q * 4;

  // diagonal column n: lane with q==cl holds it at element ce
  const int cl = (n & 31) >> 2;
  const int ce = (n & 3) + ((n >= 32) ? 4 : 0);
  float msel[8];
#pragma unroll
  for (int j = 0; j < 8; ++j) msel[j] = (q == cl && j == ce) ? 1.f : 0.f;

  float prev[8];

  float ent_sum = 0.f, ent_s2 = 0.f, ent_max = -1e30f, ent_min = 1e30f;
  float ent_first = 0.f, ent_last = 0.f;
  float diff_sum = 0.f, diff_s2 = 0.f, diff_max = -1e30f;
  float diag_sum = 0.f, diag_s2 = 0.f;

  float4 ca0, ca1, cb0, cb1;  // current pair (rows t, t+1)

  // prologue: issue pair-0 loads, then handle the overlap row (t0-1) if any
  ca0 = *(const float4*)(rowp);
  ca1 = *(const float4*)(rowp + 32);
  cb0 = *(const float4*)(rowp + tstride);
  cb1 = *(const float4*)(rowp + tstride + 32);

  if (c > 0) {
    const float* po = rowp - tstride;
    float4 o0 = *(const float4*)(po);
    float4 o1 = *(const float4*)(po + 32);
    float x[8] = {o0.x, o0.y, o0.z, o0.w, o1.x, o1.y, o1.z, o1.w};
    float e[8], s = 0.f;
#pragma unroll
    for (int j = 0; j < 8; ++j) {
      float ee = __expf(x[j]);
      e[j] = ee;
      s += ee;
    }
    s = qsum(s);
    const float inv = 1.0f / s;
#pragma unroll
    for (int j = 0; j < 8; ++j) prev[j] = e[j] * inv;
  } else {
#pragma unroll
    for (int j = 0; j < 8; ++j) prev[j] = 0.f;  // dl at t=0 is discarded
  }
  rowp += 2 * tstride;  // points at pair 1

  for (int i = 0; i < 8; ++i) {
    float4 na0, na1, nb0, nb1;
    if (i < 7) {  // prefetch next pair (guarded: last pair of last chunk OOB)
      na0 = *(const float4*)(rowp);
      na1 = *(const float4*)(rowp + 32);
      nb0 = *(const float4*)(rowp + tstride);
      nb1 = *(const float4*)(rowp + tstride + 32);
      rowp += 2 * tstride;
    }

    float xa[8] = {ca0.x, ca0.y, ca0.z, ca0.w, ca1.x, ca1.y, ca1.z, ca1.w};
    float xb[8] = {cb0.x, cb0.y, cb0.z, cb0.w, cb1.x, cb1.y, cb1.z, cb1.w};

    // e = exp(x); S = sum e; D = sum e*x  (no max-shift)
    float ea[8], eb[8];
    float sa = 0.f, da = 0.f, sb = 0.f, db = 0.f;
#pragma unroll
    for (int j = 0; j < 8; ++j) {
      const float eea = __expf(xa[j]), eeb = __expf(xb[j]);
      ea[j] = eea;
      eb[j] = eeb;
      sa += eea;
      da += eea * xa[j];
      sb += eeb;
      db += eeb * xb[j];
    }
    sa = qsum(sa);
    da = qsum(da);
    sb = qsum(sb);
    db = qsum(db);
    const float inva = 1.0f / sa, invb = 1.0f / sb;
    float ent_a = __logf(sa) - da * inva;  // = -sum p ln p (EPS clip inactive)
    float ent_b = __logf(sb) - db * invb;

    // p, |dP| vs previous row, diag select
    float dla = 0.f, dlb = 0.f, dga = 0.f, dgb = 0.f;
#pragma unroll
    for (int j = 0; j < 8; ++j) {
      const float pa = ea[j] * inva;
      const float pb = eb[j] * invb;
      dla += fabsf(pa - prev[j]);
      dlb += fabsf(pb - pa);
      dga = fmaf(pa, msel[j], dga);
      dgb = fmaf(pb, msel[j], dgb);
      prev[j] = pb;
    }

    dla = fsum(dla);
    dlb = fsum(dlb);
    // ent/dg: head reduce only (per-head value complete per lane already;
    // masks {8,16,32} toggle h bits, preserve q -> q==cl lanes get head-sum)
    ent_a = hsum(ent_a);
    ent_b = hsum(ent_b);
    dga = hsum(dga);
    dgb = hsum(dgb);

    ent_a *= 0.125f;
    ent_b *= 0.125f;
    dla *= 0.125f;
    dlb *= 0.125f;
    dga *= 0.125f;
    dgb *= 0.125f;

    // accumulate time-stats (shifted sumsq: kills fp32 cancellation in std)
    const float za = ent_a - K_ENT, zb = ent_b - K_ENT;
    ent_sum += ent_a + ent_b;
    ent_s2 += za * za + zb * zb;
    ent_max = fmaxf(ent_max, fmaxf(ent_a, ent_b));
    ent_min = fminf(ent_min, fminf(ent_a, ent_b));
    if (!(c == 0 && i == 0)) {  // dl at t=0 undefined (wave-uniform branch)
      const float wa = dla - K_DIF;
      diff_sum += dla;
      diff_s2 += wa * wa;
      diff_max = fmaxf(diff_max, dla);
    }
    const float wb = dlb - K_DIF;
    diff_sum += dlb;
    diff_s2 += wb * wb;
    diff_max = fmaxf(diff_max, dlb);
    diag_sum += dga + dgb;          // correct only in q==cl lanes (by design)
    diag_s2 += dga * dga + dgb * dgb;
    if (c == 0 && i == 0) ent_first = ent_a;
    if (c == NCHUNK - 1 && i == 7) ent_last = ent_b;

    ca0 = na0;
    ca1 = na1;
    cb0 = nb0;
    cb1 = nb1;
  }

  // diag stats live in lanes with q==cl; lane `cl` (h=0,q=cl) has them
  const float dsum = __shfl(diag_sum, cl, 64);
  const float ds2 = __shfl(diag_s2, cl, 64);

  if (lane == 0) {
    float* o = part + (size_t)((b * N_ + n) * NCHUNK + c) * 12;
    o[0] = ent_sum;  o[1] = ent_s2;  o[2] = ent_max;  o[3] = ent_min;
    o[4] = ent_first; o[5] = ent_last;
    o[6] = diff_sum; o[7] = diff_s2; o[8] = diff_max;
    o[9] = dsum;     o[10] = ds2;
  }
}

// ---------------------------------------------------------------------------
// Kernel 2: per-batch combine -> 9 features/node -> LayerNorm -> 576x64 matvec
// + ReLU. 256 threads: wave 0 does stats+LN into LDS; all 4 waves split the
// 576-long dot product 4-way then LDS-reduce.
// ---------------------------------------------------------------------------
__global__ __launch_bounds__(256) void head_kernel(
    const float* __restrict__ part, const float* __restrict__ gamma,
    const float* __restrict__ beta, const float* __restrict__ W,
    const float* __restrict__ bias, float* __restrict__ out) {
  const int b = blockIdx.x;
  const int tid = threadIdx.x;
  const int lane = tid & 63;   // output column / node index
  const int wv = tid >> 6;     // k-segment

  __shared__ float xn[N_ * 9];
  __shared__ float red[4][N_];

  if (wv == 0) {
    float ent_sum = 0.f, ent_s2 = 0.f, ent_max = -1e30f, ent_min = 1e30f;
    float ent_first = 0.f, ent_last = 0.f;
    float diff_sum = 0.f, diff_s2 = 0.f, diff_max = -1e30f;
    float diag_sum = 0.f, diag_s2 = 0.f;

    const float* base = part + ((size_t)b * N_ + lane) * NCHUNK * 12;
#pragma unroll
    for (int c = 0; c < NCHUNK; ++c) {
      const float* o = base + c * 12;
      ent_sum += o[0];
      ent_s2 += o[1];
      ent_max = fmaxf(ent_max, o[2]);
      ent_min = fminf(ent_min, o[3]);
      if (c == 0) ent_first = o[4];
      if (c == NCHUNK - 1) ent_last = o[5];
      diff_sum += o[6];
      diff_s2 += o[7];
      diff_max = fmaxf(diff_max, o[8]);
      diag_sum += o[9];
      diag_s2 += o[10];
    }

    float f[9];
    const float em = ent_sum * (1.f / 128.f);
    const float emz = em - K_ENT;
    f[0] = em;
    f[1] = sqrtf(fmaxf(ent_s2 * (1.f / 128.f) - emz * emz, 0.f));
    f[2] = ent_max - ent_min;
    f[3] = (ent_last - ent_first) * (1.f / 127.f);
    const float dm = diff_sum * (1.f / 127.f);
    const float dmz = dm - K_DIF;
    f[4] = dm;
    f[5] = sqrtf(fmaxf(diff_s2 * (1.f / 127.f) - dmz * dmz, 0.f));
    f[6] = diff_max;
    const float gm = diag_sum * (1.f / 128.f);
    f[7] = gm;
    f[8] = sqrtf(fmaxf(diag_s2 * (1.f / 128.f) - gm * gm, 0.f));

    // LayerNorm over the 576 features
    float ls = 0.f;
#pragma unroll
    for (int k = 0; k < 9; ++k) ls += f[k];
#pragma unroll
    for (int w = 1; w < 64; w <<= 1) ls += __shfl_xor(ls, w, 64);
    const float mu = ls * (1.f / 576.f);

    float lv = 0.f;
#pragma unroll
    for (int k = 0; k < 9; ++k) {
      const float dd = f[k] - mu;
      lv += dd * dd;
    }
#pragma unroll
    for (int w = 1; w < 64; w <<= 1) lv += __shfl_xor(lv, w, 64);
    const float rstd = rsqrtf(lv * (1.f / 576.f) + 1e-5f);

#pragma unroll
    for (int k = 0; k < 9; ++k) {
      const int idx = lane * 9 + k;
      xn[idx] = (f[k] - mu) * rstd * gamma[idx] + beta[idx];
    }
  }
  __syncthreads();

  // out[b, col] = relu(sum_k xn[k] * W[k,col] + bias[col]); k split 4-way
  float acc = 0.f;
  const int k0 = wv * 144;
#pragma unroll 8
  for (int k = k0; k < k0 + 144; ++k) acc = fmaf(xn[k], W[k * 64 + lane], acc);
  red[wv][lane] = acc;
  __syncthreads();

  if (wv == 0) {
    const float r =
        red[0][lane] + red[1][lane] + red[2][lane] + red[3][lane] + bias[lane];
    out[b * 64 + lane] = fmaxf(r, 0.f);
  }
}

extern "C" void kernel_launch(void* const* d_in, const int* in_sizes, int n_in,
                              void* d_out, int out_size, void* d_ws,
                              size_t ws_size, hipStream_t stream) {
  const float* sat = (const float*)d_in[0];
  const float* gamma = (const float*)d_in[1];
  const float* beta = (const float*)d_in[2];
  const float* W = (const float*)d_in[3];
  const float* bias = (const float*)d_in[4];
  float* out = (float*)d_out;
  float* part = (float*)d_ws;  // NUNITS * 12 floats = 384 KiB

  feat_partial_kernel<<<NUNITS / 4, 256, 0, stream>>>(sat, part);
  head_kernel<<<B_, 256, 0, stream>>>(part, gamma, beta, W, bias, out);
}

// Round 6
// 57.260 us; speedup vs baseline: 1.0591x; 1.0591x over previous
//
#include <hip/hip_runtime.h>
#include <hip/hip_bf16.h>
#include <math.h>

#define B_ 16
#define T_ 128
#define H_ 8
#define N_ 64
#define NCHUNK 4
#define CHUNK (T_ / NCHUNK)   // 32
#define NPAIR (CHUNK / 2)     // 16
#define NUNITS (B_ * N_ * NCHUNK)  // 4096

#define K_ENT 4.0f   // variance shift for entropy (ent ~ 3.9); exact math for any K
#define K_DIF 0.75f  // variance shift for diff

typedef float f32x4 __attribute__((ext_vector_type(4)));

__device__ __forceinline__ f32x4 ntload(const float* p) {
  return __builtin_nontemporal_load((const f32x4*)p);
}

// ---- cross-lane add helpers -------------------------------------------------
// DPP (VALU pipe): xor1 = quad_perm[1,0,3,2] (0xB1), xor2 = quad_perm[2,3,0,1]
// (0x4E), xor8 = row_ror:8 (0x128). ds_swizzle for xor4/xor16; shfl for 32.
template <int CTRL>
__device__ __forceinline__ float dpp_xadd(float x) {
  const int yi = __builtin_amdgcn_update_dpp(
      __float_as_int(x), __float_as_int(x), CTRL, 0xf, 0xf, false);
  return x + __int_as_float(yi);
}
template <int IMM>
__device__ __forceinline__ float swz_xadd(float x) {
  return x + __int_as_float(
                 __builtin_amdgcn_ds_swizzle(__float_as_int(x), IMM));
}
// sum over q (lane&7): masks {1,2,4}
__device__ __forceinline__ float qsum(float x) {
  x = dpp_xadd<0xB1>(x);
  x = dpp_xadd<0x4E>(x);
  x = swz_xadd<0x101F>(x);
  return x;
}
// sum over h (lane>>3): masks {8,16,32}
__device__ __forceinline__ float hsum(float x) {
  x = dpp_xadd<0x128>(x);
  x = swz_xadd<0x401F>(x);
  x += __shfl_xor(x, 32, 64);
  return x;
}
// full 64-lane sum
__device__ __forceinline__ float fsum(float x) {
  x = dpp_xadd<0xB1>(x);
  x = dpp_xadd<0x4E>(x);
  x = swz_xadd<0x101F>(x);
  x = dpp_xadd<0x128>(x);
  x = swz_xadd<0x401F>(x);
  x += __shfl_xor(x, 32, 64);
  return x;
}

// ---------------------------------------------------------------------------
// Kernel 1: one WAVE per (b, n, chunk). Lane l = h*8 + q: head h owns cols
// [4q,4q+4) and [32+4q,32+4q+4). Two timesteps per iteration; nontemporal
// streaming loads; launch_bounds pins >=4 waves/EU for latency hiding.
// ---------------------------------------------------------------------------
__global__ __launch_bounds__(256, 4) void feat_partial_kernel(
    const float* __restrict__ sat, float* __restrict__ part) {
  const int wave = threadIdx.x >> 6;
  const int lane = threadIdx.x & 63;
  const int unit = blockIdx.x * 4 + wave;   // c*1024 + b*64 + n
  const int c = unit >> 10;
  const int bn = unit & 1023;
  const int b = bn >> 6;
  const int n = bn & 63;

  const int q = lane & 7;
  const int h = lane >> 3;

  const int t0 = c * CHUNK;

  const long long tstride = (long long)H_ * N_ * N_;  // 32768 elems
  const float* rowp = sat +
      ((((long long)(b * T_ + t0) * H_ + h) * N_ + n) * N_) + q * 4;

  // diagonal column n: lane with q==cl holds it at element ce
  const int cl = (n & 31) >> 2;
  const int ce = (n & 3) + ((n >= 32) ? 4 : 0);
  float msel[8];
#pragma unroll
  for (int j = 0; j < 8; ++j) msel[j] = (q == cl && j == ce) ? 1.f : 0.f;

  float prev[8];

  float ent_sum = 0.f, ent_s2 = 0.f, ent_max = -1e30f, ent_min = 1e30f;
  float ent_first = 0.f, ent_last = 0.f;
  float diff_sum = 0.f, diff_s2 = 0.f, diff_max = -1e30f;
  float diag_sum = 0.f, diag_s2 = 0.f;

  f32x4 ca0, ca1, cb0, cb1;  // current pair (rows t, t+1)

  // prologue: issue pair-0 loads, then handle the overlap row (t0-1) if any
  ca0 = ntload(rowp);
  ca1 = ntload(rowp + 32);
  cb0 = ntload(rowp + tstride);
  cb1 = ntload(rowp + tstride + 32);

  if (c > 0) {
    const float* po = rowp - tstride;
    f32x4 o0 = ntload(po);
    f32x4 o1 = ntload(po + 32);
    float x[8] = {o0[0], o0[1], o0[2], o0[3], o1[0], o1[1], o1[2], o1[3]};
    float e[8], s = 0.f;
#pragma unroll
    for (int j = 0; j < 8; ++j) {
      float ee = __expf(x[j]);
      e[j] = ee;
      s += ee;
    }
    s = qsum(s);
    const float inv = 1.0f / s;
#pragma unroll
    for (int j = 0; j < 8; ++j) prev[j] = e[j] * inv;
  } else {
#pragma unroll
    for (int j = 0; j < 8; ++j) prev[j] = 0.f;  // dl at t=0 is discarded
  }
  rowp += 2 * tstride;  // points at pair 1

  for (int i = 0; i < NPAIR; ++i) {
    f32x4 na0, na1, nb0, nb1;
    if (i < NPAIR - 1) {  // prefetch next pair (guarded: last pair OOB)
      na0 = ntload(rowp);
      na1 = ntload(rowp + 32);
      nb0 = ntload(rowp + tstride);
      nb1 = ntload(rowp + tstride + 32);
      rowp += 2 * tstride;
    }

    float xa[8] = {ca0[0], ca0[1], ca0[2], ca0[3], ca1[0], ca1[1], ca1[2], ca1[3]};
    float xb[8] = {cb0[0], cb0[1], cb0[2], cb0[3], cb1[0], cb1[1], cb1[2], cb1[3]};

    // e = exp(x); S = sum e; D = sum e*x  (no max-shift: |logits| small)
    float ea[8], eb[8];
    float sa = 0.f, da = 0.f, sb = 0.f, db = 0.f;
#pragma unroll
    for (int j = 0; j < 8; ++j) {
      const float eea = __expf(xa[j]), eeb = __expf(xb[j]);
      ea[j] = eea;
      eb[j] = eeb;
      sa += eea;
      da += eea * xa[j];
      sb += eeb;
      db += eeb * xb[j];
    }
    sa = qsum(sa);
    da = qsum(da);
    sb = qsum(sb);
    db = qsum(db);
    const float inva = 1.0f / sa, invb = 1.0f / sb;
    float ent_a = __logf(sa) - da * inva;  // = -sum p ln p (EPS clip inactive)
    float ent_b = __logf(sb) - db * invb;

    // p, |dP| vs previous row, diag select
    float dla = 0.f, dlb = 0.f, dga = 0.f, dgb = 0.f;
#pragma unroll
    for (int j = 0; j < 8; ++j) {
      const float pa = ea[j] * inva;
      const float pb = eb[j] * invb;
      dla += fabsf(pa - prev[j]);
      dlb += fabsf(pb - pa);
      dga = fmaf(pa, msel[j], dga);
      dgb = fmaf(pb, msel[j], dgb);
      prev[j] = pb;
    }

    dla = fsum(dla);
    dlb = fsum(dlb);
    // ent/dg: head reduce only (masks {8,16,32} preserve q -> q==cl lanes
    // end with the full head-sum)
    ent_a = hsum(ent_a);
    ent_b = hsum(ent_b);
    dga = hsum(dga);
    dgb = hsum(dgb);

    ent_a *= 0.125f;
    ent_b *= 0.125f;
    dla *= 0.125f;
    dlb *= 0.125f;
    dga *= 0.125f;
    dgb *= 0.125f;

    // accumulate time-stats (shifted sumsq: kills fp32 cancellation in std)
    const float za = ent_a - K_ENT, zb = ent_b - K_ENT;
    ent_sum += ent_a + ent_b;
    ent_s2 += za * za + zb * zb;
    ent_max = fmaxf(ent_max, fmaxf(ent_a, ent_b));
    ent_min = fminf(ent_min, fminf(ent_a, ent_b));
    if (!(c == 0 && i == 0)) {  // dl at t=0 undefined (wave-uniform branch)
      const float wa = dla - K_DIF;
      diff_sum += dla;
      diff_s2 += wa * wa;
      diff_max = fmaxf(diff_max, dla);
    }
    const float wb = dlb - K_DIF;
    diff_sum += dlb;
    diff_s2 += wb * wb;
    diff_max = fmaxf(diff_max, dlb);
    diag_sum += dga + dgb;          // correct only in q==cl lanes (by design)
    diag_s2 += dga * dga + dgb * dgb;
    if (c == 0 && i == 0) ent_first = ent_a;
    if (c == NCHUNK - 1 && i == NPAIR - 1) ent_last = ent_b;

    ca0 = na0;
    ca1 = na1;
    cb0 = nb0;
    cb1 = nb1;
  }

  // diag stats live in lanes with q==cl; lane `cl` (h=0,q=cl) has them
  const float dsum = __shfl(diag_sum, cl, 64);
  const float ds2 = __shfl(diag_s2, cl, 64);

  if (lane == 0) {
    float* o = part + (size_t)((b * N_ + n) * NCHUNK + c) * 12;
    o[0] = ent_sum;  o[1] = ent_s2;  o[2] = ent_max;  o[3] = ent_min;
    o[4] = ent_first; o[5] = ent_last;
    o[6] = diff_sum; o[7] = diff_s2; o[8] = diff_max;
    o[9] = dsum;     o[10] = ds2;
  }
}

// ---------------------------------------------------------------------------
// Kernel 2: per-batch combine -> 9 features/node -> LayerNorm -> 576x64 matvec
// + ReLU. 256 threads: wave 0 does stats+LN into LDS; all 4 waves split the
// 576-long dot product 4-way then LDS-reduce.
// ---------------------------------------------------------------------------
__global__ __launch_bounds__(256) void head_kernel(
    const float* __restrict__ part, const float* __restrict__ gamma,
    const float* __restrict__ beta, const float* __restrict__ W,
    const float* __restrict__ bias, float* __restrict__ out) {
  const int b = blockIdx.x;
  const int tid = threadIdx.x;
  const int lane = tid & 63;   // output column / node index
  const int wv = tid >> 6;     // k-segment

  __shared__ float xn[N_ * 9];
  __shared__ float red[4][N_];

  if (wv == 0) {
    float ent_sum = 0.f, ent_s2 = 0.f, ent_max = -1e30f, ent_min = 1e30f;
    float ent_first = 0.f, ent_last = 0.f;
    float diff_sum = 0.f, diff_s2 = 0.f, diff_max = -1e30f;
    float diag_sum = 0.f, diag_s2 = 0.f;

    const float* base = part + ((size_t)b * N_ + lane) * NCHUNK * 12;
#pragma unroll
    for (int c = 0; c < NCHUNK; ++c) {
      const float* o = base + c * 12;
      ent_sum += o[0];
      ent_s2 += o[1];
      ent_max = fmaxf(ent_max, o[2]);
      ent_min = fminf(ent_min, o[3]);
      if (c == 0) ent_first = o[4];
      if (c == NCHUNK - 1) ent_last = o[5];
      diff_sum += o[6];
      diff_s2 += o[7];
      diff_max = fmaxf(diff_max, o[8]);
      diag_sum += o[9];
      diag_s2 += o[10];
    }

    float f[9];
    const float em = ent_sum * (1.f / 128.f);
    const float emz = em - K_ENT;
    f[0] = em;
    f[1] = sqrtf(fmaxf(ent_s2 * (1.f / 128.f) - emz * emz, 0.f));
    f[2] = ent_max - ent_min;
    f[3] = (ent_last - ent_first) * (1.f / 127.f);
    const float dm = diff_sum * (1.f / 127.f);
    const float dmz = dm - K_DIF;
    f[4] = dm;
    f[5] = sqrtf(fmaxf(diff_s2 * (1.f / 127.f) - dmz * dmz, 0.f));
    f[6] = diff_max;
    const float gm = diag_sum * (1.f / 128.f);
    f[7] = gm;
    f[8] = sqrtf(fmaxf(diag_s2 * (1.f / 128.f) - gm * gm, 0.f));

    // LayerNorm over the 576 features
    float ls = 0.f;
#pragma unroll
    for (int k = 0; k < 9; ++k) ls += f[k];
#pragma unroll
    for (int w = 1; w < 64; w <<= 1) ls += __shfl_xor(ls, w, 64);
    const float mu = ls * (1.f / 576.f);

    float lv = 0.f;
#pragma unroll
    for (int k = 0; k < 9; ++k) {
      const float dd = f[k] - mu;
      lv += dd * dd;
    }
#pragma unroll
    for (int w = 1; w < 64; w <<= 1) lv += __shfl_xor(lv, w, 64);
    const float rstd = rsqrtf(lv * (1.f / 576.f) + 1e-5f);

#pragma unroll
    for (int k = 0; k < 9; ++k) {
      const int idx = lane * 9 + k;
      xn[idx] = (f[k] - mu) * rstd * gamma[idx] + beta[idx];
    }
  }
  __syncthreads();

  // out[b, col] = relu(sum_k xn[k] * W[k,col] + bias[col]); k split 4-way
  float acc = 0.f;
  const int k0 = wv * 144;
#pragma unroll 8
  for (int k = k0; k < k0 + 144; ++k) acc = fmaf(xn[k], W[k * 64 + lane], acc);
  red[wv][lane] = acc;
  __syncthreads();

  if (wv == 0) {
    const float r =
        red[0][lane] + red[1][lane] + red[2][lane] + red[3][lane] + bias[lane];
    out[b * 64 + lane] = fmaxf(r, 0.f);
  }
}

extern "C" void kernel_launch(void* const* d_in, const int* in_sizes, int n_in,
                              void* d_out, int out_size, void* d_ws,
                              size_t ws_size, hipStream_t stream) {
  const float* sat = (const float*)d_in[0];
  const float* gamma = (const float*)d_in[1];
  const float* beta = (const float*)d_in[2];
  const float* W = (const float*)d_in[3];
  const float* bias = (const float*)d_in[4];
  float* out = (float*)d_out;
  float* part = (float*)d_ws;  // NUNITS * 12 floats = 192 KiB

  feat_partial_kernel<<<NUNITS / 4, 256, 0, stream>>>(sat, part);
  head_kernel<<<B_, 256, 0, stream>>>(part, gamma, beta, W, bias, out);
}